// Round 3
// baseline (1765.934 us; speedup 1.0000x reference)
//
#include <hip/hip_runtime.h>

#define N_NODES  50000
#define N_EDGES  1600000
#define NODE_DIM 1024
#define HID      128
#define LN_EPS   1e-5f
#define NBUCK    196              // dst>>8 buckets (256 nodes each)
#define SHARD    6250             // N_EDGES / 256
#define BSTR     132              // padded LDS accumulator stride (anti-conflict)

typedef float f32x4 __attribute__((ext_vector_type(4)));
typedef __bf16 bf16x8 __attribute__((ext_vector_type(8)));
typedef unsigned short u16x8 __attribute__((ext_vector_type(8)));

// HW bf16 convert: gfx950 lowers fptrunc f32->bf16 to v_cvt_pk_bf16_f32 (RNE)
__device__ __forceinline__ unsigned short f2bf(float f) {
  __bf16 b = (__bf16)f;
  return __builtin_bit_cast(unsigned short, b);
}
__device__ __forceinline__ unsigned int pkbf(float a, float b) {
  return (unsigned int)f2bf(a) | ((unsigned int)f2bf(b) << 16);
}
__device__ __forceinline__ float bf2f(unsigned short v) {
  return __uint_as_float((unsigned int)v << 16);
}

// 256-wide exclusive scan (all 256 threads participate)
__device__ __forceinline__ int scan256_excl(int v, int buf[2][256], int t) {
  int cur = 0;
  buf[0][t] = v;
  __syncthreads();
  for (int off = 1; off < 256; off <<= 1) {
    int nxt = cur ^ 1;
    int s = buf[cur][t];
    if (t >= off) s += buf[cur][t - off];
    buf[nxt][t] = s;
    cur = nxt;
    __syncthreads();
  }
  return buf[cur][t] - v;
}

// ---------------------------------------------------------------------------
// K1: h = bf16(relu(x @ proj_w^T + proj_b)), K-step 64 (two 32-sub-tiles)
// ---------------------------------------------------------------------------
__global__ __launch_bounds__(256) void k_proj(const float* __restrict__ x,
                                              const float* __restrict__ pw,
                                              const float* __restrict__ pb,
                                              unsigned short* __restrict__ h) {
  __shared__ unsigned short As[2][128][32];
  __shared__ unsigned short Bs[2][128][32];
  const int tid = threadIdx.x;
  const int m0 = blockIdx.x * 128;
  const int wave = tid >> 6, lane = tid & 63;
  const int wm = (wave >> 1) * 64, wn = (wave & 1) * 64;
  const int srow = tid >> 1;
  const int sub  = tid & 1;            // which K-half this thread stages
  const int fr = lane & 15, ko = (lane >> 4) * 8;

  f32x4 acc[4][4] = {};
  const int arow = m0 + srow;
  const bool aval = (arow < N_NODES);
  const float* xrow = x + (size_t)arow * NODE_DIM + sub * 32;
  const float* brow = pw + (size_t)srow * NODE_DIM + sub * 32;

  for (int k0 = 0; k0 < NODE_DIM; k0 += 64) {
    float4 av[8], bv[8];
    if (aval) {
      const float4* p = (const float4*)(xrow + k0);
#pragma unroll
      for (int j = 0; j < 8; j++) av[j] = p[j];
    } else {
#pragma unroll
      for (int j = 0; j < 8; j++) av[j] = make_float4(0.f, 0.f, 0.f, 0.f);
    }
    const float4* q = (const float4*)(brow + k0);
#pragma unroll
    for (int j = 0; j < 8; j++) bv[j] = q[j];

    __syncthreads();
    unsigned int* da = (unsigned int*)&As[sub][srow][0];
    unsigned int* db = (unsigned int*)&Bs[sub][srow][0];
#pragma unroll
    for (int j = 0; j < 8; j++) {
      da[2 * j]     = pkbf(av[j].x, av[j].y);
      da[2 * j + 1] = pkbf(av[j].z, av[j].w);
      db[2 * j]     = pkbf(bv[j].x, bv[j].y);
      db[2 * j + 1] = pkbf(bv[j].z, bv[j].w);
    }
    __syncthreads();

#pragma unroll
    for (int s = 0; s < 2; s++) {
      bf16x8 af[4], bfr[4];
#pragma unroll
      for (int m = 0; m < 4; m++)
        af[m] = *(const bf16x8*)&As[s][wm + m * 16 + fr][ko];
#pragma unroll
      for (int n = 0; n < 4; n++)
        bfr[n] = *(const bf16x8*)&Bs[s][wn + n * 16 + fr][ko];
#pragma unroll
      for (int m = 0; m < 4; m++)
#pragma unroll
        for (int n = 0; n < 4; n++)
          acc[m][n] = __builtin_amdgcn_mfma_f32_16x16x32_bf16(af[m], bfr[n], acc[m][n], 0, 0, 0);
    }
  }

  const int cr = (lane >> 4) * 4, cc = lane & 15;
#pragma unroll
  for (int n = 0; n < 4; n++) {
    const int col = wn + n * 16 + cc;
    const float bias = pb[col];
#pragma unroll
    for (int m = 0; m < 4; m++) {
#pragma unroll
      for (int i = 0; i < 4; i++) {
        const int row = m0 + wm + m * 16 + cr + i;
        if (row < N_NODES) {
          float v = acc[m][n][i] + bias;
          h[(size_t)row * HID + col] = f2bf(v > 0.f ? v : 0.f);
        }
      }
    }
  }
}

// ---------------------------------------------------------------------------
// CSR-lite build: hist -> scan -> scan -> scatter (packed u32 pairs)
// ---------------------------------------------------------------------------
__global__ __launch_bounds__(256) void k_hist(const int* __restrict__ ei,
                                              int* __restrict__ counts) {
  __shared__ int bins[NBUCK];
  int t = threadIdx.x;
  if (t < NBUCK) bins[t] = 0;
  __syncthreads();
  int base = blockIdx.x * SHARD;
  for (int i = t; i < SHARD; i += 256)
    atomicAdd(&bins[ei[N_EDGES + base + i] >> 8], 1);
  __syncthreads();
  if (t < NBUCK) counts[t * 256 + blockIdx.x] = bins[t];
}

__global__ __launch_bounds__(256) void k_s1(const int* __restrict__ counts,
                                            int* __restrict__ basem,
                                            int* __restrict__ btot) {
  __shared__ int buf[2][256];
  int t = threadIdx.x, b = blockIdx.x;
  int v = counts[b * 256 + t];
  int excl = scan256_excl(v, buf, t);
  basem[b * 256 + t] = excl;
  if (t == 255) btot[b] = excl + v;
}

__global__ __launch_bounds__(256) void k_s2(const int* __restrict__ btot,
                                            int* __restrict__ bstart,
                                            float* __restrict__ accum) {
  __shared__ int buf[2][256];
  int t = threadIdx.x;
  int v = (t < NBUCK) ? btot[t] : 0;
  int excl = scan256_excl(v, buf, t);
  if (t < NBUCK) bstart[t] = excl;
  if (t == 0) bstart[NBUCK] = N_EDGES;
  if (t < HID) accum[t] = 0.f;
}

__global__ __launch_bounds__(256) void k_scatter(const int* __restrict__ ei,
                                                 const int* __restrict__ basem,
                                                 const int* __restrict__ bstart,
                                                 unsigned int* __restrict__ bs) {
  __shared__ int cur[NBUCK];
  int t = threadIdx.x;
  if (t < NBUCK) cur[t] = bstart[t] + basem[t * 256 + blockIdx.x];
  __syncthreads();
  int base = blockIdx.x * SHARD;
  for (int i = t; i < SHARD; i += 256) {
    int e = base + i;
    unsigned int src = (unsigned int)ei[e];
    unsigned int dst = (unsigned int)ei[N_EDGES + e];
    int pos = atomicAdd(&cur[dst >> 8], 1);
    bs[pos] = src | ((dst & 255u) << 16);
  }
}

// ---------------------------------------------------------------------------
// K_AGG: fused per-bucket aggregation + mean. One 1024-thread block per
// bucket; 256x132 fp32 accumulator in LDS; ds_add_f32 with per-lane feat
// rotation (2-way bank aliasing = free). Writes mean_nbr bf16.
// ---------------------------------------------------------------------------
__global__ __launch_bounds__(1024) void k_agg(const int* __restrict__ bstart,
                                              const unsigned int* __restrict__ bs,
                                              const unsigned short* __restrict__ h,
                                              unsigned short* __restrict__ mn) {
  __shared__ float acc[256 * BSTR];   // 135168 B
  __shared__ int degL[256];
  const int t = threadIdx.x, b = blockIdx.x;
  for (int i = t; i < 256 * BSTR; i += 1024) acc[i] = 0.f;
  if (t < 256) degL[t] = 0;
  __syncthreads();

  const int s = bstart[b], e = bstart[b + 1];
  const int grp = t >> 4, li = t & 15;
  int i = s + grp;
  for (; i + 64 < e; i += 128) {
    unsigned int p0 = bs[i], p1 = bs[i + 64];
    const u16x8 v0 = *(const u16x8*)(h + (size_t)(p0 & 0xffffu) * HID + li * 8);
    const u16x8 v1 = *(const u16x8*)(h + (size_t)(p1 & 0xffffu) * HID + li * 8);
    const int d0 = p0 >> 16, d1 = p1 >> 16;
    if (li == 0) { atomicAdd(&degL[d0], 1); atomicAdd(&degL[d1], 1); }
    float* a0 = &acc[d0 * BSTR + li * 8];
    float* a1 = &acc[d1 * BSTR + li * 8];
#pragma unroll
    for (int j = 0; j < 8; j++) {
      int jj = (j + li) & 7;
      atomicAdd(&a0[jj], bf2f(v0[jj]));
    }
#pragma unroll
    for (int j = 0; j < 8; j++) {
      int jj = (j + li) & 7;
      atomicAdd(&a1[jj], bf2f(v1[jj]));
    }
  }
  if (i < e) {
    unsigned int p0 = bs[i];
    const u16x8 v0 = *(const u16x8*)(h + (size_t)(p0 & 0xffffu) * HID + li * 8);
    const int d0 = p0 >> 16;
    if (li == 0) atomicAdd(&degL[d0], 1);
    float* a0 = &acc[d0 * BSTR + li * 8];
#pragma unroll
    for (int j = 0; j < 8; j++) {
      int jj = (j + li) & 7;
      atomicAdd(&a0[jj], bf2f(v0[jj]));
    }
  }
  __syncthreads();

  const int node0 = b * 256;
  for (int i2 = t; i2 < 256 * 64; i2 += 1024) {
    int nl = i2 >> 6, fp = (i2 & 63) * 2;
    int node = node0 + nl;
    if (node < N_NODES) {
      float inv = 1.f / fmaxf((float)degL[nl], 1.f);
      *(unsigned int*)(mn + (size_t)node * HID + fp) =
          pkbf(acc[nl * BSTR + fp] * inv, acc[nl * BSTR + fp + 1] * inv);
    }
  }
}

// ---------------------------------------------------------------------------
// K_SAGE: h2 = [mn|h] @ [wl|wr]^T + lb, fused LayerNorm+ReLU+mean-pool.
// h2 never hits global memory: per m-tile 32x128 LDS transpose strip.
// ---------------------------------------------------------------------------
__global__ __launch_bounds__(256) void k_sage(const unsigned short* __restrict__ mn,
                                              const unsigned short* __restrict__ h,
                                              const float* __restrict__ wl,
                                              const float* __restrict__ wr,
                                              const float* __restrict__ lb,
                                              const float* __restrict__ lg,
                                              const float* __restrict__ lbt,
                                              float* __restrict__ accum) {
  __shared__ unsigned short As[128 * 32];
  __shared__ unsigned short Bs[128 * 32];
  __shared__ float T3[32 * 128];       // 16 KB transpose strip
  __shared__ float red[4][128];
  const int tid = threadIdx.x;
  const int m0 = blockIdx.x * 128;
  const int wave = tid >> 6, lane = tid & 63;
  const int wm = (wave >> 1) * 64, wn = (wave & 1) * 64;
  const int srow = tid >> 1, scol = (tid & 1) * 16;
  const int fr = lane & 15, ko = (lane >> 4) * 8;

  f32x4 acc[4][4] = {};

  for (int k0 = 0; k0 < 2 * HID; k0 += 32) {
    const unsigned short* baseA = (k0 < HID) ? mn : h;
    const float* baseB = (k0 < HID) ? wl : wr;
    const int kk = (k0 & (HID - 1)) + scol;
    const int arow = m0 + srow;
    u16x8 a0 = {0, 0, 0, 0, 0, 0, 0, 0}, a1 = a0;
    if (arow < N_NODES) {
      const u16x8* p = (const u16x8*)(baseA + (size_t)arow * HID + kk);
      a0 = p[0]; a1 = p[1];
    }
    const float4* q = (const float4*)(baseB + (size_t)srow * HID + kk);
    float4 b0 = q[0], b1 = q[1], b2 = q[2], b3 = q[3];

    __syncthreads();
    *(u16x8*)&As[srow * 32 + scol]     = a0;
    *(u16x8*)&As[srow * 32 + scol + 8] = a1;
    unsigned int* db = (unsigned int*)&Bs[srow * 32 + scol];
    db[0] = pkbf(b0.x, b0.y); db[1] = pkbf(b0.z, b0.w);
    db[2] = pkbf(b1.x, b1.y); db[3] = pkbf(b1.z, b1.w);
    db[4] = pkbf(b2.x, b2.y); db[5] = pkbf(b2.z, b2.w);
    db[6] = pkbf(b3.x, b3.y); db[7] = pkbf(b3.z, b3.w);
    __syncthreads();

    bf16x8 af[4], bfr[4];
#pragma unroll
    for (int m = 0; m < 4; m++)
      af[m] = *(const bf16x8*)&As[(wm + m * 16 + fr) * 32 + ko];
#pragma unroll
    for (int n = 0; n < 4; n++)
      bfr[n] = *(const bf16x8*)&Bs[(wn + n * 16 + fr) * 32 + ko];
#pragma unroll
    for (int m = 0; m < 4; m++)
#pragma unroll
      for (int n = 0; n < 4; n++)
        acc[m][n] = __builtin_amdgcn_mfma_f32_16x16x32_bf16(af[m], bfr[n], acc[m][n], 0, 0, 0);
  }

  // fused LN + ReLU + pool
  const int cr = (lane >> 4) * 4, cc = lane & 15;
  const int p = wave >> 1;
  const float g0 = lg[lane], g1 = lg[lane + 64];
  const float t0 = lbt[lane], t1 = lbt[lane + 64];
  float ax = 0.f, ay = 0.f;
#pragma unroll
  for (int m = 0; m < 4; m++) {
    __syncthreads();   // previous strip fully read
#pragma unroll
    for (int n = 0; n < 4; n++) {
      const int col = wn + n * 16 + cc;
      const float bias = lb[col];
#pragma unroll
      for (int i = 0; i < 4; i++)
        T3[(p * 16 + cr + i) * 128 + col] = acc[m][n][i] + bias;
    }
    __syncthreads();
    for (int r8 = 0; r8 < 8; r8++) {
      int q8 = wave * 8 + r8;                       // 0..31
      int grow = m0 + (q8 >> 4) * 64 + m * 16 + (q8 & 15);
      float v0 = T3[q8 * 128 + lane];
      float v1 = T3[q8 * 128 + lane + 64];
      float sum = v0 + v1, ss = v0 * v0 + v1 * v1;
#pragma unroll
      for (int off = 32; off > 0; off >>= 1) {
        sum += __shfl_xor(sum, off);
        ss  += __shfl_xor(ss, off);
      }
      float mu  = sum * (1.f / HID);
      float var = ss * (1.f / HID) - mu * mu;
      float rinv = rsqrtf(var + LN_EPS);
      if (grow < N_NODES) {
        float y0 = (v0 - mu) * rinv * g0 + t0;
        float y1 = (v1 - mu) * rinv * g1 + t1;
        ax += fmaxf(y0, 0.f);
        ay += fmaxf(y1, 0.f);
      }
    }
  }
  red[wave][lane]      = ax;
  red[wave][lane + 64] = ay;
  __syncthreads();
  if (wave == 0) {
    float a  = red[0][lane] + red[1][lane] + red[2][lane] + red[3][lane];
    float bb = red[0][lane + 64] + red[1][lane + 64] + red[2][lane + 64] + red[3][lane + 64];
    atomicAdd(&accum[lane], a);
    atomicAdd(&accum[lane + 64], bb);
  }
}

// ---------------------------------------------------------------------------
// K_FINAL: out = (accum/N) @ out_w^T + out_b
// ---------------------------------------------------------------------------
__global__ __launch_bounds__(128) void k_final(const float* __restrict__ accum,
                                               const float* __restrict__ ow,
                                               const float* __restrict__ ob,
                                               float* __restrict__ out) {
  __shared__ float gs[HID];
  int t = threadIdx.x;
  gs[t] = accum[t] * (1.f / N_NODES);
  __syncthreads();
  float s = ob[t];
  for (int k = 0; k < HID; k++) s += gs[k] * ow[t * HID + k];
  out[t] = s;
}

// ---------------------------------------------------------------------------
extern "C" void kernel_launch(void* const* d_in, const int* in_sizes, int n_in,
                              void* d_out, int out_size, void* d_ws, size_t ws_size,
                              hipStream_t stream) {
  const float* x   = (const float*)d_in[0];
  const int*   ei  = (const int*)d_in[1];
  const float* pw  = (const float*)d_in[2];
  const float* pb  = (const float*)d_in[3];
  const float* wl  = (const float*)d_in[4];
  const float* lb  = (const float*)d_in[5];
  const float* wr  = (const float*)d_in[6];
  const float* lg  = (const float*)d_in[7];
  const float* lbt = (const float*)d_in[8];
  const float* ow  = (const float*)d_in[9];
  const float* ob  = (const float*)d_in[10];
  float* out = (float*)d_out;

  const int PAD = NBUCK * 256;  // 50176
  unsigned short* h  = (unsigned short*)d_ws;             // PAD*128 bf16
  unsigned short* mn = h + (size_t)PAD * HID;             // PAD*128 bf16
  unsigned int* bsp  = (unsigned int*)(mn + (size_t)PAD * HID); // E packed
  int* counts = (int*)(bsp + N_EDGES);                    // NBUCK*256
  int* basem  = counts + NBUCK * 256;                     // NBUCK*256
  int* btot   = basem + NBUCK * 256;                      // 256
  int* bstart = btot + 256;                               // 256 (NBUCK+1 used)
  float* accum = (float*)(bstart + 256);                  // 128

  const int MB = (N_NODES + 127) / 128;   // 391

  hipLaunchKernelGGL(k_proj,    dim3(MB),    dim3(256),  0, stream, x, pw, pb, h);
  hipLaunchKernelGGL(k_hist,    dim3(256),   dim3(256),  0, stream, ei, counts);
  hipLaunchKernelGGL(k_s1,      dim3(NBUCK), dim3(256),  0, stream, counts, basem, btot);
  hipLaunchKernelGGL(k_s2,      dim3(1),     dim3(256),  0, stream, btot, bstart, accum);
  hipLaunchKernelGGL(k_scatter, dim3(256),   dim3(256),  0, stream, ei, basem, bstart, bsp);
  hipLaunchKernelGGL(k_agg,     dim3(NBUCK), dim3(1024), 0, stream, bstart, bsp, h, mn);
  hipLaunchKernelGGL(k_sage,    dim3(MB),    dim3(256),  0, stream, mn, h, wl, wr, lb, lg, lbt, accum);
  hipLaunchKernelGGL(k_final,   dim3(1),     dim3(128),  0, stream, accum, ow, ob, out);
}

// Round 4
// 473.992 us; speedup vs baseline: 3.7257x; 3.7257x over previous
//
#include <hip/hip_runtime.h>

#define N_NODES  50000
#define N_EDGES  1600000
#define NODE_DIM 1024
#define HID      128
#define LN_EPS   1e-5f
#define NBUCK    196              // dst>>8 buckets (256 nodes each)
#define SHARD    6250             // N_EDGES / 256

typedef float f32x4 __attribute__((ext_vector_type(4)));
typedef __bf16 bf16x8 __attribute__((ext_vector_type(8)));
typedef unsigned short u16x8 __attribute__((ext_vector_type(8)));

// HW bf16 convert: gfx950 lowers fptrunc f32->bf16 to v_cvt_pk_bf16_f32 (RNE)
__device__ __forceinline__ unsigned short f2bf(float f) {
  __bf16 b = (__bf16)f;
  return __builtin_bit_cast(unsigned short, b);
}
__device__ __forceinline__ unsigned int pkbf(float a, float b) {
  return (unsigned int)f2bf(a) | ((unsigned int)f2bf(b) << 16);
}
__device__ __forceinline__ float bf2f(unsigned short v) {
  return __uint_as_float((unsigned int)v << 16);
}

__device__ __forceinline__ int scan256_excl(int v, int buf[2][256], int t) {
  int cur = 0;
  buf[0][t] = v;
  __syncthreads();
  for (int off = 1; off < 256; off <<= 1) {
    int nxt = cur ^ 1;
    int s = buf[cur][t];
    if (t >= off) s += buf[cur][t - off];
    buf[nxt][t] = s;
    cur = nxt;
    __syncthreads();
  }
  return buf[cur][t] - v;
}

// ---------------------------------------------------------------------------
// K1: h = bf16(relu(x @ proj_w^T + proj_b)), K-step 64
// ---------------------------------------------------------------------------
__global__ __launch_bounds__(256) void k_proj(const float* __restrict__ x,
                                              const float* __restrict__ pw,
                                              const float* __restrict__ pb,
                                              unsigned short* __restrict__ h) {
  __shared__ unsigned short As[2][128][32];
  __shared__ unsigned short Bs[2][128][32];
  const int tid = threadIdx.x;
  const int m0 = blockIdx.x * 128;
  const int wave = tid >> 6, lane = tid & 63;
  const int wm = (wave >> 1) * 64, wn = (wave & 1) * 64;
  const int srow = tid >> 1;
  const int sub  = tid & 1;
  const int fr = lane & 15, ko = (lane >> 4) * 8;

  f32x4 acc[4][4] = {};
  const int arow = m0 + srow;
  const bool aval = (arow < N_NODES);
  const float* xrow = x + (size_t)arow * NODE_DIM + sub * 32;
  const float* brow = pw + (size_t)srow * NODE_DIM + sub * 32;

  for (int k0 = 0; k0 < NODE_DIM; k0 += 64) {
    float4 av[8], bv[8];
    if (aval) {
      const float4* p = (const float4*)(xrow + k0);
#pragma unroll
      for (int j = 0; j < 8; j++) av[j] = p[j];
    } else {
#pragma unroll
      for (int j = 0; j < 8; j++) av[j] = make_float4(0.f, 0.f, 0.f, 0.f);
    }
    const float4* q = (const float4*)(brow + k0);
#pragma unroll
    for (int j = 0; j < 8; j++) bv[j] = q[j];

    __syncthreads();
    unsigned int* da = (unsigned int*)&As[sub][srow][0];
    unsigned int* db = (unsigned int*)&Bs[sub][srow][0];
#pragma unroll
    for (int j = 0; j < 8; j++) {
      da[2 * j]     = pkbf(av[j].x, av[j].y);
      da[2 * j + 1] = pkbf(av[j].z, av[j].w);
      db[2 * j]     = pkbf(bv[j].x, bv[j].y);
      db[2 * j + 1] = pkbf(bv[j].z, bv[j].w);
    }
    __syncthreads();

#pragma unroll
    for (int s = 0; s < 2; s++) {
      bf16x8 af[4], bfr[4];
#pragma unroll
      for (int m = 0; m < 4; m++)
        af[m] = *(const bf16x8*)&As[s][wm + m * 16 + fr][ko];
#pragma unroll
      for (int n = 0; n < 4; n++)
        bfr[n] = *(const bf16x8*)&Bs[s][wn + n * 16 + fr][ko];
#pragma unroll
      for (int m = 0; m < 4; m++)
#pragma unroll
        for (int n = 0; n < 4; n++)
          acc[m][n] = __builtin_amdgcn_mfma_f32_16x16x32_bf16(af[m], bfr[n], acc[m][n], 0, 0, 0);
    }
  }

  const int cr = (lane >> 4) * 4, cc = lane & 15;
#pragma unroll
  for (int n = 0; n < 4; n++) {
    const int col = wn + n * 16 + cc;
    const float bias = pb[col];
#pragma unroll
    for (int m = 0; m < 4; m++) {
#pragma unroll
      for (int i = 0; i < 4; i++) {
        const int row = m0 + wm + m * 16 + cr + i;
        if (row < N_NODES) {
          float v = acc[m][n][i] + bias;
          h[(size_t)row * HID + col] = f2bf(v > 0.f ? v : 0.f);
        }
      }
    }
  }
}

// ---------------------------------------------------------------------------
// CSR build: hist -> scan -> scan -> scatter(packed) -> per-bucket CSR
// ---------------------------------------------------------------------------
__global__ __launch_bounds__(256) void k_hist(const int* __restrict__ ei,
                                              int* __restrict__ counts) {
  __shared__ int bins[NBUCK];
  int t = threadIdx.x;
  if (t < NBUCK) bins[t] = 0;
  __syncthreads();
  int base = blockIdx.x * SHARD;
  for (int i = t; i < SHARD; i += 256)
    atomicAdd(&bins[ei[N_EDGES + base + i] >> 8], 1);
  __syncthreads();
  if (t < NBUCK) counts[t * 256 + blockIdx.x] = bins[t];
}

__global__ __launch_bounds__(256) void k_s1(const int* __restrict__ counts,
                                            int* __restrict__ basem,
                                            int* __restrict__ btot) {
  __shared__ int buf[2][256];
  int t = threadIdx.x, b = blockIdx.x;
  int v = counts[b * 256 + t];
  int excl = scan256_excl(v, buf, t);
  basem[b * 256 + t] = excl;
  if (t == 255) btot[b] = excl + v;
}

__global__ __launch_bounds__(256) void k_s2(const int* __restrict__ btot,
                                            int* __restrict__ bstart,
                                            float* __restrict__ accum) {
  __shared__ int buf[2][256];
  int t = threadIdx.x;
  int v = (t < NBUCK) ? btot[t] : 0;
  int excl = scan256_excl(v, buf, t);
  if (t < NBUCK) bstart[t] = excl;
  if (t == 0) bstart[NBUCK] = N_EDGES;
  if (t < HID) accum[t] = 0.f;
}

__global__ __launch_bounds__(256) void k_scatter(const int* __restrict__ ei,
                                                 const int* __restrict__ basem,
                                                 const int* __restrict__ bstart,
                                                 unsigned int* __restrict__ bs) {
  __shared__ int cur[NBUCK];
  int t = threadIdx.x;
  if (t < NBUCK) cur[t] = bstart[t] + basem[t * 256 + blockIdx.x];
  __syncthreads();
  int base = blockIdx.x * SHARD;
  for (int i = t; i < SHARD; i += 256) {
    int e = base + i;
    unsigned int src = (unsigned int)ei[e];
    unsigned int dst = (unsigned int)ei[N_EDGES + e];
    int pos = atomicAdd(&cur[dst >> 8], 1);
    bs[pos] = src | ((dst & 255u) << 16);
  }
}

// per-bucket exact CSR (LDS atomics on 1 cursor/edge only); nbr as u16
__global__ __launch_bounds__(256) void k_bucket(const int* __restrict__ bstart,
                                                const unsigned int* __restrict__ bs,
                                                unsigned short* __restrict__ nbr,
                                                int* __restrict__ offs,
                                                int* __restrict__ deg) {
  __shared__ int bins[256];
  __shared__ int buf[2][256];
  __shared__ int curs[256];
  int t = threadIdx.x, b = blockIdx.x;
  int s = bstart[b], e = bstart[b + 1];
  bins[t] = 0;
  __syncthreads();
  for (int i = s + t; i < e; i += 256)
    atomicAdd(&bins[(bs[i] >> 16) & 255u], 1);
  __syncthreads();
  int v = bins[t];
  int excl = scan256_excl(v, buf, t);
  int node = b * 256 + t;
  deg[node]  = v;
  offs[node] = s + excl;
  curs[t]    = s + excl;
  __syncthreads();
  for (int i = s + t; i < e; i += 256) {
    unsigned int p = bs[i];
    int pos = atomicAdd(&curs[(p >> 16) & 255u], 1);
    nbr[pos] = (unsigned short)(p & 0xffffu);
  }
}

// ---------------------------------------------------------------------------
// K_GATHER: mean over neighbors. One wave/node; 4 groups x 16 lanes x 16B;
// 2x unroll -> 8 row-loads in flight per wave.
// ---------------------------------------------------------------------------
__global__ __launch_bounds__(256) void k_gather(const unsigned short* __restrict__ h,
                                                const unsigned short* __restrict__ nbr,
                                                const int* __restrict__ offs,
                                                const int* __restrict__ deg,
                                                unsigned short* __restrict__ mn) {
  const int wave = threadIdx.x >> 6;
  const int lane = threadIdx.x & 63;
  const int node = blockIdx.x * 4 + wave;
  if (node >= N_NODES) return;
  const int g = lane >> 4, li = lane & 15;
  const int d  = deg[node];
  const int st = offs[node];
  float a[8] = {0.f, 0.f, 0.f, 0.f, 0.f, 0.f, 0.f, 0.f};
  int n = g;
  for (; n + 4 < d; n += 8) {
    int s0 = nbr[st + n];
    int s1 = nbr[st + n + 4];
    u16x8 v0 = *(const u16x8*)(h + (size_t)s0 * HID + li * 8);
    u16x8 v1 = *(const u16x8*)(h + (size_t)s1 * HID + li * 8);
#pragma unroll
    for (int k = 0; k < 8; k++) a[k] += bf2f(v0[k]) + bf2f(v1[k]);
  }
  if (n < d) {
    int s0 = nbr[st + n];
    u16x8 v0 = *(const u16x8*)(h + (size_t)s0 * HID + li * 8);
#pragma unroll
    for (int k = 0; k < 8; k++) a[k] += bf2f(v0[k]);
  }
#pragma unroll
  for (int k = 0; k < 8; k++) {
    a[k] += __shfl_xor(a[k], 16);
    a[k] += __shfl_xor(a[k], 32);
  }
  if (g == 0) {
    float inv = 1.f / fmaxf((float)d, 1.f);
    u16x8 r;
#pragma unroll
    for (int k = 0; k < 8; k++) r[k] = f2bf(a[k] * inv);
    *(u16x8*)(mn + (size_t)node * HID + li * 8) = r;
  }
}

// ---------------------------------------------------------------------------
// K_SAGE: h2 = [mn|h] @ [wl|wr]^T + lb, fused LayerNorm+ReLU+mean-pool.
// h2 never hits global memory (validated in R3).
// ---------------------------------------------------------------------------
__global__ __launch_bounds__(256) void k_sage(const unsigned short* __restrict__ mn,
                                              const unsigned short* __restrict__ h,
                                              const float* __restrict__ wl,
                                              const float* __restrict__ wr,
                                              const float* __restrict__ lb,
                                              const float* __restrict__ lg,
                                              const float* __restrict__ lbt,
                                              float* __restrict__ accum) {
  __shared__ unsigned short As[128 * 32];
  __shared__ unsigned short Bs[128 * 32];
  __shared__ float T3[32 * 128];
  __shared__ float red[4][128];
  const int tid = threadIdx.x;
  const int m0 = blockIdx.x * 128;
  const int wave = tid >> 6, lane = tid & 63;
  const int wm = (wave >> 1) * 64, wn = (wave & 1) * 64;
  const int srow = tid >> 1, scol = (tid & 1) * 16;
  const int fr = lane & 15, ko = (lane >> 4) * 8;

  f32x4 acc[4][4] = {};

  for (int k0 = 0; k0 < 2 * HID; k0 += 32) {
    const unsigned short* baseA = (k0 < HID) ? mn : h;
    const float* baseB = (k0 < HID) ? wl : wr;
    const int kk = (k0 & (HID - 1)) + scol;
    const int arow = m0 + srow;
    u16x8 a0 = {0, 0, 0, 0, 0, 0, 0, 0}, a1 = a0;
    if (arow < N_NODES) {
      const u16x8* p = (const u16x8*)(baseA + (size_t)arow * HID + kk);
      a0 = p[0]; a1 = p[1];
    }
    const float4* q = (const float4*)(baseB + (size_t)srow * HID + kk);
    float4 b0 = q[0], b1 = q[1], b2 = q[2], b3 = q[3];

    __syncthreads();
    *(u16x8*)&As[srow * 32 + scol]     = a0;
    *(u16x8*)&As[srow * 32 + scol + 8] = a1;
    unsigned int* db = (unsigned int*)&Bs[srow * 32 + scol];
    db[0] = pkbf(b0.x, b0.y); db[1] = pkbf(b0.z, b0.w);
    db[2] = pkbf(b1.x, b1.y); db[3] = pkbf(b1.z, b1.w);
    db[4] = pkbf(b2.x, b2.y); db[5] = pkbf(b2.z, b2.w);
    db[6] = pkbf(b3.x, b3.y); db[7] = pkbf(b3.z, b3.w);
    __syncthreads();

    bf16x8 af[4], bfr[4];
#pragma unroll
    for (int m = 0; m < 4; m++)
      af[m] = *(const bf16x8*)&As[(wm + m * 16 + fr) * 32 + ko];
#pragma unroll
    for (int n = 0; n < 4; n++)
      bfr[n] = *(const bf16x8*)&Bs[(wn + n * 16 + fr) * 32 + ko];
#pragma unroll
    for (int m = 0; m < 4; m++)
#pragma unroll
      for (int n = 0; n < 4; n++)
        acc[m][n] = __builtin_amdgcn_mfma_f32_16x16x32_bf16(af[m], bfr[n], acc[m][n], 0, 0, 0);
  }

  const int cr = (lane >> 4) * 4, cc = lane & 15;
  const int p = wave >> 1;
  const float g0 = lg[lane], g1 = lg[lane + 64];
  const float t0 = lbt[lane], t1 = lbt[lane + 64];
  float ax = 0.f, ay = 0.f;
#pragma unroll
  for (int m = 0; m < 4; m++) {
    __syncthreads();
#pragma unroll
    for (int n = 0; n < 4; n++) {
      const int col = wn + n * 16 + cc;
      const float bias = lb[col];
#pragma unroll
      for (int i = 0; i < 4; i++)
        T3[(p * 16 + cr + i) * 128 + col] = acc[m][n][i] + bias;
    }
    __syncthreads();
    for (int r8 = 0; r8 < 8; r8++) {
      int q8 = wave * 8 + r8;
      int grow = m0 + (q8 >> 4) * 64 + m * 16 + (q8 & 15);
      float v0 = T3[q8 * 128 + lane];
      float v1 = T3[q8 * 128 + lane + 64];
      float sum = v0 + v1, ss = v0 * v0 + v1 * v1;
#pragma unroll
      for (int off = 32; off > 0; off >>= 1) {
        sum += __shfl_xor(sum, off);
        ss  += __shfl_xor(ss, off);
      }
      float mu  = sum * (1.f / HID);
      float var = ss * (1.f / HID) - mu * mu;
      float rinv = rsqrtf(var + LN_EPS);
      if (grow < N_NODES) {
        float y0 = (v0 - mu) * rinv * g0 + t0;
        float y1 = (v1 - mu) * rinv * g1 + t1;
        ax += fmaxf(y0, 0.f);
        ay += fmaxf(y1, 0.f);
      }
    }
  }
  red[wave][lane]      = ax;
  red[wave][lane + 64] = ay;
  __syncthreads();
  if (wave == 0) {
    float a  = red[0][lane] + red[1][lane] + red[2][lane] + red[3][lane];
    float bb = red[0][lane + 64] + red[1][lane + 64] + red[2][lane + 64] + red[3][lane + 64];
    atomicAdd(&accum[lane], a);
    atomicAdd(&accum[lane + 64], bb);
  }
}

// ---------------------------------------------------------------------------
__global__ __launch_bounds__(128) void k_final(const float* __restrict__ accum,
                                               const float* __restrict__ ow,
                                               const float* __restrict__ ob,
                                               float* __restrict__ out) {
  __shared__ float gs[HID];
  int t = threadIdx.x;
  gs[t] = accum[t] * (1.f / N_NODES);
  __syncthreads();
  float s = ob[t];
  for (int k = 0; k < HID; k++) s += gs[k] * ow[t * HID + k];
  out[t] = s;
}

// ---------------------------------------------------------------------------
extern "C" void kernel_launch(void* const* d_in, const int* in_sizes, int n_in,
                              void* d_out, int out_size, void* d_ws, size_t ws_size,
                              hipStream_t stream) {
  const float* x   = (const float*)d_in[0];
  const int*   ei  = (const int*)d_in[1];
  const float* pw  = (const float*)d_in[2];
  const float* pb  = (const float*)d_in[3];
  const float* wl  = (const float*)d_in[4];
  const float* lb  = (const float*)d_in[5];
  const float* wr  = (const float*)d_in[6];
  const float* lg  = (const float*)d_in[7];
  const float* lbt = (const float*)d_in[8];
  const float* ow  = (const float*)d_in[9];
  const float* ob  = (const float*)d_in[10];
  float* out = (float*)d_out;

  const int PAD = NBUCK * 256;  // 50176
  unsigned short* h  = (unsigned short*)d_ws;                   // PAD*128 bf16
  unsigned short* mn = h + (size_t)PAD * HID;                   // PAD*128 bf16
  unsigned int* bsp  = (unsigned int*)(mn + (size_t)PAD * HID); // E packed u32
  unsigned short* nbr = (unsigned short*)(bsp + N_EDGES);       // E u16
  int* counts = (int*)(nbr + N_EDGES);                          // NBUCK*256
  int* basem  = counts + NBUCK * 256;
  int* btot   = basem + NBUCK * 256;                            // 256
  int* bstart = btot + 256;                                     // 256
  int* offs   = bstart + 256;                                   // PAD
  int* deg    = offs + PAD;                                     // PAD
  float* accum = (float*)(deg + PAD);                           // 128

  const int MB = (N_NODES + 127) / 128;   // 391

  hipLaunchKernelGGL(k_proj,    dim3(MB),    dim3(256), 0, stream, x, pw, pb, h);
  hipLaunchKernelGGL(k_hist,    dim3(256),   dim3(256), 0, stream, ei, counts);
  hipLaunchKernelGGL(k_s1,      dim3(NBUCK), dim3(256), 0, stream, counts, basem, btot);
  hipLaunchKernelGGL(k_s2,      dim3(1),     dim3(256), 0, stream, btot, bstart, accum);
  hipLaunchKernelGGL(k_scatter, dim3(256),   dim3(256), 0, stream, ei, basem, bstart, bsp);
  hipLaunchKernelGGL(k_bucket,  dim3(NBUCK), dim3(256), 0, stream, bstart, bsp, nbr, offs, deg);
  hipLaunchKernelGGL(k_gather,  dim3((N_NODES + 3) / 4), dim3(256), 0, stream, h, nbr, offs, deg, mn);
  hipLaunchKernelGGL(k_sage,    dim3(MB),    dim3(256), 0, stream, mn, h, wl, wr, lb, lg, lbt, accum);
  hipLaunchKernelGGL(k_final,   dim3(1),     dim3(128), 0, stream, accum, ow, ob, out);
}